// Round 1
// baseline (2168.435 us; speedup 1.0000x reference)
//
#include <hip/hip_runtime.h>

#define TLEN 2048
#define BSZ  2048
#define HIDD 128
#define HALF 64
#define RPW  16
#define STRH 136   // bf16 element stride for h1/h2 LDS tiles (conflict-spread, 16B-align ok)
#define STR3 68    // f32 stride for h3act LDS tile

typedef float f32x4 __attribute__((ext_vector_type(4)));
typedef short bf16x8 __attribute__((ext_vector_type(8)));

__device__ __forceinline__ unsigned short f2b(float f) {
    union { float f; unsigned u; } v; v.f = f;
    unsigned r = v.u + 0x7FFFu + ((v.u >> 16) & 1u);   // RNE to bf16
    return (unsigned short)(r >> 16);
}

__global__ __launch_bounds__(256, 1) void garch_scan_kernel(
    const float* __restrict__ returns, const float* __restrict__ log_rv,
    const float* __restrict__ p_omega, const float* __restrict__ p_beta,
    const float* __restrict__ p_tau1,  const float* __restrict__ p_tau2,
    const float* __restrict__ p_gamma, const float* __restrict__ p_xi,
    const float* __restrict__ p_phi,   const float* __restrict__ p_delta1,
    const float* __restrict__ p_delta2,const float* __restrict__ p_mu,
    const float* __restrict__ W1, const float* __restrict__ b1,
    const float* __restrict__ W2, const float* __restrict__ b2,
    const float* __restrict__ W3, const float* __restrict__ b3,
    const float* __restrict__ W4, const float* __restrict__ b4,
    float* __restrict__ out)
{
    const int tid  = threadIdx.x;
    const int w    = tid >> 6;     // wave 0..3
    const int lane = tid & 63;
    const int c16  = lane & 15;
    const int g    = lane >> 4;

    __shared__ unsigned short h1buf[RPW * STRH];
    __shared__ unsigned short h2buf[RPW * STRH];
    __shared__ float          h3act[RPW * STR3];

    const float omega = p_omega[0], beta = p_beta[0], tau1 = p_tau1[0],
                tau2 = p_tau2[0],  gma  = p_gamma[0], xi  = p_xi[0],
                phi  = p_phi[0],   d1   = p_delta1[0], d2 = p_delta2[0],
                mu   = p_mu[0],    b4s  = b4[0];

    const int grow = blockIdx.x * RPW + c16;   // this lane's batch row

    // ---------------- prologue: weight fragments into registers ----------------
    // B-fragment slot (g,e) of K-tile kk holds W[32*kk + 8*g + e][col].
    // A-fragments are read from LDS with the identical k-slot assignment, so the
    // contraction is correct independent of the HW's internal k ordering.
    bf16x8 w1f[2], w2f[4][2], w3f[4];
    float b1v[2], b2v[2], b3v;
    float w4r[16];
    #pragma unroll
    for (int ntl = 0; ntl < 2; ++ntl) {
        const int col = 32*w + 16*ntl + c16;
        b1v[ntl] = b1[col];
        b2v[ntl] = b2[col];
        bf16x8 a;
        #pragma unroll
        for (int e = 0; e < 8; ++e) {
            const int k = 8*g + e;
            ((unsigned short*)&a)[e] = (k < 5) ? f2b(W1[k*HIDD + col]) : (unsigned short)0;
        }
        w1f[ntl] = a;
        #pragma unroll
        for (int kk = 0; kk < 4; ++kk) {
            bf16x8 bfr;
            #pragma unroll
            for (int e = 0; e < 8; ++e) {
                const int k = 32*kk + 8*g + e;
                ((unsigned short*)&bfr)[e] = f2b(W2[k*HIDD + col]);
            }
            w2f[kk][ntl] = bfr;
        }
    }
    {
        const int col3 = 16*w + c16;
        b3v = b3[col3];
        #pragma unroll
        for (int kk = 0; kk < 4; ++kk) {
            bf16x8 bfr;
            #pragma unroll
            for (int e = 0; e < 8; ++e) {
                const int k = 32*kk + 8*g + e;
                ((unsigned short*)&bfr)[e] = f2b(W3[k*HALF + col3]);
            }
            w3f[kk] = bfr;
        }
    }
    #pragma unroll
    for (int j = 0; j < 16; ++j) w4r[j] = W4[16*g + j];

    // ---------------- scan state ----------------
    float lh_c = 0.f, z_c = 0.f, lx_c = 0.f;
    float r_cur   = returns[grow*TLEN];
    float lrv_cur = log_rv[grow*TLEN];
    int ti = 0, di = 0;   // t % 78, (t/78) % 5

    for (int t = 0; t < TLEN; ++t) {
        // prefetch next step's inputs (latency hidden behind this step)
        float r_nxt = 0.f, lrv_nxt = 0.f;
        if (t + 1 < TLEN) {
            r_nxt   = returns[grow*TLEN + t + 1];
            lrv_nxt = log_rv[grow*TLEN + t + 1];
        }

        // ---- recurrence (fp32, per-lane, row = c16, replicated across g and waves) ----
        float lh;
        if (t == 0) lh = lrv_cur;   // log(exp(log_rv[:,0])) == log_rv[:,0]
        else lh = omega + beta*lh_c + tau1*z_c + tau2*(z_c*z_c - 1.f) + gma*lx_c;
        const float zv  = (r_cur - mu) * __expf(-0.5f * lh);
        const float lx  = xi + phi*lh + d1*zv + d2*(zv*zv - 1.f);
        const float uv  = lrv_cur - lx;
        const float tod = (float)ti * (1.f/77.f);
        const float dow = (float)di * 0.25f;

        // ---- layer 1: feat(16x5 padded to K=32) @ W1 -> h1 cols [32w,32w+32) ----
        bf16x8 a1 = {0,0,0,0,0,0,0,0};
        if (g == 0) {
            unsigned short* ap = (unsigned short*)&a1;
            ap[0]=f2b(lh); ap[1]=f2b(zv); ap[2]=f2b(uv); ap[3]=f2b(tod); ap[4]=f2b(dow);
        }
        #pragma unroll
        for (int ntl = 0; ntl < 2; ++ntl) {
            f32x4 z4 = {0.f,0.f,0.f,0.f};
            f32x4 acc = __builtin_amdgcn_mfma_f32_16x16x32_bf16(a1, w1f[ntl], z4, 0,0,0);
            const int col = 32*w + 16*ntl + c16;
            #pragma unroll
            for (int i = 0; i < 4; ++i) {
                float x = acc[i] + b1v[ntl];
                x = fmaxf(x, 0.1f*x);                     // LeakyReLU(0.1)
                h1buf[(4*g + i)*STRH + col] = f2b(x);     // C/D: col=lane&15, row=4g+i
            }
        }
        __syncthreads();

        // ---- layer 2: h1(16x128) @ W2 -> h2 cols [32w,32w+32) ----
        bf16x8 a2[4];
        #pragma unroll
        for (int kk = 0; kk < 4; ++kk)
            a2[kk] = *(const bf16x8*)(h1buf + c16*STRH + 32*kk + 8*g);  // one ds_read_b128
        f32x4 acc2[2] = {{0.f,0.f,0.f,0.f},{0.f,0.f,0.f,0.f}};
        #pragma unroll
        for (int kk = 0; kk < 4; ++kk) {
            #pragma unroll
            for (int ntl = 0; ntl < 2; ++ntl)
                acc2[ntl] = __builtin_amdgcn_mfma_f32_16x16x32_bf16(a2[kk], w2f[kk][ntl], acc2[ntl], 0,0,0);
        }
        #pragma unroll
        for (int ntl = 0; ntl < 2; ++ntl) {
            const int col = 32*w + 16*ntl + c16;
            #pragma unroll
            for (int i = 0; i < 4; ++i) {
                float x = acc2[ntl][i] + b2v[ntl];
                x = fmaxf(x, 0.1f*x);
                h2buf[(4*g + i)*STRH + col] = f2b(x);
            }
        }
        __syncthreads();

        // ---- layer 3: h2(16x128) @ W3 -> h3 cols [16w,16w+16) ----
        bf16x8 a3[4];
        #pragma unroll
        for (int kk = 0; kk < 4; ++kk)
            a3[kk] = *(const bf16x8*)(h2buf + c16*STRH + 32*kk + 8*g);
        f32x4 acc3 = {0.f,0.f,0.f,0.f};
        #pragma unroll
        for (int kk = 0; kk < 4; ++kk)
            acc3 = __builtin_amdgcn_mfma_f32_16x16x32_bf16(a3[kk], w3f[kk], acc3, 0,0,0);
        {
            const int col3 = 16*w + c16;
            #pragma unroll
            for (int i = 0; i < 4; ++i) {
                float x = acc3[i] + b3v;
                x = fmaxf(x, 0.1f*x);
                h3act[(4*g + i)*STR3 + col3] = x;         // fp32 for the final dot
            }
        }
        __syncthreads();

        // ---- layer 4: h3(16x64) @ W4 (64->1), every lane computes its row's value ----
        const float4* hp = (const float4*)(h3act + c16*STR3 + 16*g);
        const float4 q0 = hp[0], q1 = hp[1], q2 = hp[2], q3 = hp[3];
        float p;
        p = q0.x * w4r[0];
        p = fmaf(q0.y, w4r[1],  p); p = fmaf(q0.z, w4r[2],  p); p = fmaf(q0.w, w4r[3],  p);
        p = fmaf(q1.x, w4r[4],  p); p = fmaf(q1.y, w4r[5],  p); p = fmaf(q1.z, w4r[6],  p);
        p = fmaf(q1.w, w4r[7],  p); p = fmaf(q2.x, w4r[8],  p); p = fmaf(q2.y, w4r[9],  p);
        p = fmaf(q2.z, w4r[10], p); p = fmaf(q2.w, w4r[11], p); p = fmaf(q3.x, w4r[12], p);
        p = fmaf(q3.y, w4r[13], p); p = fmaf(q3.z, w4r[14], p); p = fmaf(q3.w, w4r[15], p);
        p += __shfl_xor(p, 16, 64);   // sum over g-bit0
        p += __shfl_xor(p, 32, 64);   // sum over g-bit1
        const float enh = lh + 0.01f * (p + b4s);

        // ---- outputs: (log_h, log_x, z, u) concatenated ----
        if (tid < 16) {               // wave 0, g==0: rows 0..15
            const int o = grow*TLEN + t;
            out[o]                = enh;
            out[BSZ*TLEN + o]     = lx;
            out[2*BSZ*TLEN + o]   = zv;
            out[3*BSZ*TLEN + o]   = uv;
        }

        // ---- carry ----
        lh_c = enh; z_c = zv; lx_c = lx;
        r_cur = r_nxt; lrv_cur = lrv_nxt;
        if (++ti == 78) { ti = 0; if (++di == 5) di = 0; }
    }
}

extern "C" void kernel_launch(void* const* d_in, const int* in_sizes, int n_in,
                              void* d_out, int out_size, void* d_ws, size_t ws_size,
                              hipStream_t stream) {
    (void)in_sizes; (void)n_in; (void)d_ws; (void)ws_size; (void)out_size;
    const float* returns = (const float*)d_in[0];
    const float* log_rv  = (const float*)d_in[1];
    const float* p_omega = (const float*)d_in[2];
    const float* p_beta  = (const float*)d_in[3];
    const float* p_tau1  = (const float*)d_in[4];
    const float* p_tau2  = (const float*)d_in[5];
    const float* p_gamma = (const float*)d_in[6];
    const float* p_xi    = (const float*)d_in[7];
    const float* p_phi   = (const float*)d_in[8];
    const float* p_d1    = (const float*)d_in[9];
    const float* p_d2    = (const float*)d_in[10];
    const float* p_mu    = (const float*)d_in[11];
    const float* W1 = (const float*)d_in[12];
    const float* b1 = (const float*)d_in[13];
    const float* W2 = (const float*)d_in[14];
    const float* b2 = (const float*)d_in[15];
    const float* W3 = (const float*)d_in[16];
    const float* b3 = (const float*)d_in[17];
    const float* W4 = (const float*)d_in[18];
    const float* b4 = (const float*)d_in[19];
    float* out = (float*)d_out;

    garch_scan_kernel<<<dim3(BSZ / RPW), dim3(256), 0, stream>>>(
        returns, log_rv, p_omega, p_beta, p_tau1, p_tau2, p_gamma, p_xi,
        p_phi, p_d1, p_d2, p_mu, W1, b1, W2, b2, W3, b3, W4, b4, out);
}